// Round 6
// baseline (783.905 us; speedup 1.0000x reference)
//
#include <hip/hip_runtime.h>
#include <math.h>

#define N 16384
#define NWORDS 256       // N/64
#define FEAT 512
#define NUM_CATS 65
#define K 25
#define MAX_DETS 1000

typedef unsigned long long u64;
typedef unsigned int u32x4 __attribute__((ext_vector_type(4)));

// ---------------- ws layout (bytes) ----------------
// keys     : u64[N]            @ 0         (131072)
// rank     : u32[N]            @ 131072    (65536)
// sidx     : u32[N]            @ 196608    (65536)
// sbox     : float4[N]         @ 262144    (262144)
// sarea    : f32[N]            @ 524288    (65536)
// mask     : u64[N*NWORDS]     @ 589824    (33554432)
// (gap: old idxArr, now in k_finish LDS)
// keepOrig : u8[N]             @ 34144384  (16384)
// zeropad  : u64[256]          @ 34160768  (2048)   zeroed each launch by k_build
// tdT      : u64[64*256*4]     @ 34162816  (524288) transposed diag blocks
// total ~34.7 MB

// Sort key: descending by score, ties -> ascending original index.
__global__ void k_build(const float* __restrict__ scores,
                        u64* __restrict__ keys,
                        unsigned int* __restrict__ rank,
                        u64* __restrict__ zeropad) {
    int i = blockIdx.x * 256 + threadIdx.x;
    keys[i] = ((u64)__float_as_uint(scores[i]) << 32) |
              (u64)(0xFFFFFFFFu - (unsigned)i);
    rank[i] = 0u;
    if (blockIdx.x == 0) zeropad[threadIdx.x] = 0ull;
}

// rank[i] = #{ j : key[j] > key[i] }  (keys distinct -> permutation)
__global__ void k_rank(const u64* __restrict__ keys,
                       unsigned int* __restrict__ rank) {
    __shared__ u64 lk[2048];
    int i = blockIdx.x * 256 + threadIdx.x;
    u64 my = keys[i];
    int j0 = blockIdx.y * 2048;
    for (int t = threadIdx.x; t < 2048; t += 256) lk[t] = keys[j0 + t];
    __syncthreads();
    unsigned int cnt = 0;
#pragma unroll 8
    for (int t = 0; t < 2048; ++t) cnt += (lk[t] > my) ? 1u : 0u;
    atomicAdd(&rank[i], cnt);
}

// Scatter into sorted order directly (merged old k_scatter+k_gather).
__global__ void k_scatter(const unsigned int* __restrict__ rank,
                          const float* __restrict__ det_boxes,
                          unsigned int* __restrict__ sidx,
                          float4* __restrict__ sbox,
                          float* __restrict__ sarea) {
    int i = blockIdx.x * 256 + threadIdx.x;
    unsigned p = rank[i];
    sidx[p] = (unsigned)i;
    float4 b = ((const float4*)det_boxes)[i];   // [y1,x1,y2,x2]
    sbox[p] = b;
    sarea[p] = (b.w - b.y) * (b.z - b.x);       // (x2-x1)*(y2-y1)
}

// IoU>0.6 bit matrix, 256x256-box tiles per block (4 words/thread).
// Word (row, wi) written iff col0+63 >= row; fully-lower words stay
// garbage and are only ever OR'd into already-consumed supp words.
__global__ void k_mask(const float4* __restrict__ sbox,
                       const float* __restrict__ sarea,
                       u64* __restrict__ mask) {
    int cg = blockIdx.x, rg = blockIdx.y;
    if (cg < rg) return;                    // strictly lower 256-tile
    __shared__ float4 cbox[256];
    __shared__ float carea[256];
    int tid = threadIdx.x;
    cbox[tid] = sbox[cg * 256 + tid];
    carea[tid] = sarea[cg * 256 + tid];
    __syncthreads();
    int row = rg * 256 + tid;
    float4 r = sbox[row];
    float ra = sarea[row];
    for (int cw = 0; cw < 4; ++cw) {
        int col0 = cg * 256 + cw * 64;
        if (col0 + 63 < row) continue;
        u64 bits = 0ull;
        if (col0 > row) {
            for (int j = 0; j < 64; ++j) {
                float4 cbx = cbox[cw * 64 + j];
                float iw = fminf(r.w, cbx.w) - fmaxf(r.y, cbx.y);
                iw = fmaxf(iw, 0.0f);
                float ih = fminf(r.z, cbx.z) - fmaxf(r.x, cbx.x);
                ih = fmaxf(ih, 0.0f);
                float inter = iw * ih;
                float iou = inter / (ra + carea[cw * 64 + j] - inter + 1e-12f);
                if (iou > 0.6f) bits |= (1ull << j);
            }
        } else {
            for (int j = 0; j < 64; ++j) {
                int col = col0 + j;
                if (col > row) {
                    float4 cbx = cbox[cw * 64 + j];
                    float iw = fminf(r.w, cbx.w) - fmaxf(r.y, cbx.y);
                    iw = fmaxf(iw, 0.0f);
                    float ih = fminf(r.z, cbx.z) - fmaxf(r.x, cbx.x);
                    ih = fmaxf(ih, 0.0f);
                    float inter = iw * ih;
                    float iou = inter / (ra + carea[cw * 64 + j] - inter + 1e-12f);
                    if (iou > 0.6f) bits |= (1ull << j);
                }
            }
        }
        mask[(size_t)row * NWORDS + cg * 4 + cw] = bits;
    }
}

// Transposed diagonal blocks for 256-box chunks, column-major:
// tdT[(C*256+t)*4 + w] bit r0 set iff row C*256+w*64+r0 (< t within chunk)
// suppresses column C*256+t. Same expression DAG as k_mask -> bitwise
// identical decisions.
__global__ void k_tdiag(const float4* __restrict__ sbox,
                        const float* __restrict__ sarea,
                        u64* __restrict__ tdT) {
    __shared__ float4 b[256];
    __shared__ float a[256];
    int C = blockIdx.x, t = threadIdx.x;
    b[t] = sbox[C * 256 + t];
    a[t] = sarea[C * 256 + t];
    __syncthreads();
    float4 my = b[t];
    float myarea = a[t];
#pragma unroll
    for (int w = 0; w < 4; ++w) {
        u64 bits = 0ull;
        for (int r0 = 0; r0 < 64; ++r0) {
            int r = w * 64 + r0;
            if (r < t) {
                float4 rb = b[r];                           // suppressor (row)
                float iw = fminf(rb.w, my.w) - fmaxf(rb.y, my.y);
                iw = fmaxf(iw, 0.0f);
                float ih = fminf(rb.z, my.z) - fmaxf(rb.x, my.x);
                ih = fmaxf(ih, 0.0f);
                float inter = iw * ih;
                float iou = inter / (a[r] + myarea - inter + 1e-12f);
                if (iou > 0.6f) bits |= (1ull << r0);
            }
        }
        tdT[((size_t)C * 256 + t) * 4 + w] = bits;
    }
}

// Single-wave greedy scan, 256-box chunks (64 serialized chunks instead of
// 256 — the round-5 counters showed cost is per-chunk stall, not per-keep).
// supp bitmask in registers: lane W>>2 owns global word W in reg W&3, so
// chunk c's words 4c..4c+3 all broadcast from lane c. Phase A: per
// sub-word ballot greedy; per keep = 1 ballot + 4 static u64 bit tests
// against per-lane transposed diag columns (no shfl, no indexed select).
// Phase B: proven asm batch (16 global_load_dwordx4 + one vmcnt(0) per
// <=8 kept rows). tdT for chunk c+1 prefetched during chunk c.
__global__ void __launch_bounds__(64, 1)
k_scan(const u64* __restrict__ mask,
       const u64* __restrict__ tdT,
       const unsigned int* __restrict__ sidx,
       const u64* __restrict__ zeropad,
       unsigned char* __restrict__ keepOrig) {
    __shared__ u64 keepw_arr[NWORDS];
    int lane = threadIdx.x;                       // 64 threads = 1 wave
    u64 s0 = 0, s1 = 0, s2 = 0, s3 = 0;           // supp words lane*4+0..3
    int cnt = 0;                                  // uniform across lanes
    const char* zp = (const char*)zeropad + lane * 32;

    // lane's 4 diag columns for current chunk: tdA=col lane, tdB=col 64+lane,
    // tdC=col 128+lane, tdD=col 192+lane; 4 u64 words each (rows by sub-word)
    u64 tdA0, tdA1, tdA2, tdA3, tdB0, tdB1, tdB2, tdB3;
    u64 tdC0, tdC1, tdC2, tdC3, tdD0, tdD1, tdD2, tdD3;
#define LOADTD(d0, d1, d2, d3, C, COL)                                        \
    {                                                                         \
        const ulonglong2* cp =                                                \
            (const ulonglong2*)tdT + ((size_t)(C) * 256 + (size_t)(COL)) * 2; \
        ulonglong2 x_ = cp[0], y_ = cp[1];                                    \
        d0 = x_.x; d1 = x_.y; d2 = y_.x; d3 = y_.y;                           \
    }
    LOADTD(tdA0, tdA1, tdA2, tdA3, 0, lane)
    LOADTD(tdB0, tdB1, tdB2, tdB3, 0, 64 + lane)
    LOADTD(tdC0, tdC1, tdC2, tdC3, 0, 128 + lane)
    LOADTD(tdD0, tdD1, tdD2, tdD3, 0, 192 + lane)

    for (int c = 0; c < 64; ++c) {
        if (cnt >= MAX_DETS) {                    // nothing further kept/suppressed
            for (int cc = 4 * c + lane; cc < NWORDS; cc += 64) keepw_arr[cc] = 0ull;
            break;
        }
        // broadcast supp words 4c..4c+3 (owner lane c, regs 0..3)
        u64 sw0 = __shfl(s0, c, 64);
        u64 sw1 = __shfl(s1, c, 64);
        u64 sw2 = __shfl(s2, c, 64);
        u64 sw3 = __shfl(s3, c, 64);
        bool a0 = !((sw0 >> lane) & 1ull);        // alive, column 0*64+lane
        bool a1 = !((sw1 >> lane) & 1ull);
        bool a2 = !((sw2 >> lane) & 1ull);
        bool a3 = !((sw3 >> lane) & 1ull);

        // ---- phase A: ballot greedy, sub-word by sub-word ----
        u64 kp0, kp1, kp2, kp3;
#define SUBW(W, AW, KP)                                                       \
        {                                                                     \
            u64 kw = 0ull;                                                    \
            while (cnt < MAX_DETS) {                                          \
                u64 b = __ballot(AW);                                         \
                if (!b) break;                                                \
                int kk = __ffsll((long long)b) - 1;                           \
                kw |= 1ull << kk;                                             \
                ++cnt;                                                        \
                a0 = a0 && !((tdA##W >> kk) & 1ull);                          \
                a1 = a1 && !((tdB##W >> kk) & 1ull);                          \
                a2 = a2 && !((tdC##W >> kk) & 1ull);                          \
                a3 = a3 && !((tdD##W >> kk) & 1ull);                          \
                AW = AW && (lane != kk);                                      \
            }                                                                 \
            KP = kw;                                                          \
        }
        SUBW(0, a0, kp0)
        SUBW(1, a1, kp1)
        SUBW(2, a2, kp2)
        SUBW(3, a3, kp3)
#undef SUBW
        if (lane == 0) {
            keepw_arr[4 * c + 0] = kp0;
            keepw_arr[4 * c + 1] = kp1;
            keepw_arr[4 * c + 2] = kp2;
            keepw_arr[4 * c + 3] = kp3;
        }

        // prefetch next chunk's diag columns (overlaps phase B's drain)
        u64 nA0 = 0, nA1 = 0, nA2 = 0, nA3 = 0, nB0 = 0, nB1 = 0, nB2 = 0, nB3 = 0;
        u64 nC0 = 0, nC1 = 0, nC2 = 0, nC3 = 0, nD0 = 0, nD1 = 0, nD2 = 0, nD3 = 0;
        if (c + 1 < 64) {
            LOADTD(nA0, nA1, nA2, nA3, c + 1, lane)
            LOADTD(nB0, nB1, nB2, nB3, c + 1, 64 + lane)
            LOADTD(nC0, nC1, nC2, nC3, c + 1, 128 + lane)
            LOADTD(nD0, nD1, nD2, nD3, c + 1, 192 + lane)
        }

        // ---- phase B: batched suppression OR, 8 rows per asm batch ----
        if (cnt < MAX_DETS && (kp0 | kp1 | kp2 | kp3)) {
            u64 b0 = kp0, b1 = kp1, b2 = kp2, b3 = kp3;
            size_t rbase = (size_t)c * 256;
            while (b0 | b1 | b2 | b3) {
                const char *P0, *P1, *P2, *P3, *P4, *P5, *P6, *P7;
#define FILL(Pi)                                                              \
                {                                                             \
                    size_t r_ = (size_t)-1;                                   \
                    if (b0)      { int t = __ffsll((long long)b0) - 1; b0 &= b0 - 1; r_ = rbase + t; }       \
                    else if (b1) { int t = __ffsll((long long)b1) - 1; b1 &= b1 - 1; r_ = rbase + 64 + t; }  \
                    else if (b2) { int t = __ffsll((long long)b2) - 1; b2 &= b2 - 1; r_ = rbase + 128 + t; } \
                    else if (b3) { int t = __ffsll((long long)b3) - 1; b3 &= b3 - 1; r_ = rbase + 192 + t; } \
                    Pi = (r_ == (size_t)-1) ? zp :                            \
                         (const char*)mask + ((r_ << 8) + ((size_t)lane << 2)) * 8; \
                }
                FILL(P0) FILL(P1) FILL(P2) FILL(P3)
                FILL(P4) FILL(P5) FILL(P6) FILL(P7)
#undef FILL
                u32x4 Qa0, Qb0, Qa1, Qb1, Qa2, Qb2, Qa3, Qb3;
                u32x4 Qa4, Qb4, Qa5, Qb5, Qa6, Qb6, Qa7, Qb7;
                asm volatile(
                    "global_load_dwordx4 %0, %16, off\n\t"
                    "global_load_dwordx4 %1, %16, off offset:16\n\t"
                    "global_load_dwordx4 %2, %17, off\n\t"
                    "global_load_dwordx4 %3, %17, off offset:16\n\t"
                    "global_load_dwordx4 %4, %18, off\n\t"
                    "global_load_dwordx4 %5, %18, off offset:16\n\t"
                    "global_load_dwordx4 %6, %19, off\n\t"
                    "global_load_dwordx4 %7, %19, off offset:16\n\t"
                    "global_load_dwordx4 %8, %20, off\n\t"
                    "global_load_dwordx4 %9, %20, off offset:16\n\t"
                    "global_load_dwordx4 %10, %21, off\n\t"
                    "global_load_dwordx4 %11, %21, off offset:16\n\t"
                    "global_load_dwordx4 %12, %22, off\n\t"
                    "global_load_dwordx4 %13, %22, off offset:16\n\t"
                    "global_load_dwordx4 %14, %23, off\n\t"
                    "global_load_dwordx4 %15, %23, off offset:16\n\t"
                    "s_waitcnt vmcnt(0)"
                    : "=&v"(Qa0), "=&v"(Qb0), "=&v"(Qa1), "=&v"(Qb1),
                      "=&v"(Qa2), "=&v"(Qb2), "=&v"(Qa3), "=&v"(Qb3),
                      "=&v"(Qa4), "=&v"(Qb4), "=&v"(Qa5), "=&v"(Qb5),
                      "=&v"(Qa6), "=&v"(Qb6), "=&v"(Qa7), "=&v"(Qb7)
                    : "v"(P0), "v"(P1), "v"(P2), "v"(P3),
                      "v"(P4), "v"(P5), "v"(P6), "v"(P7)
                    : "memory");
#define U64W0(q) (((u64)(q).y << 32) | (u64)(q).x)
#define U64W1(q) (((u64)(q).w << 32) | (u64)(q).z)
                s0 |= U64W0(Qa0) | U64W0(Qa1) | U64W0(Qa2) | U64W0(Qa3) |
                      U64W0(Qa4) | U64W0(Qa5) | U64W0(Qa6) | U64W0(Qa7);
                s1 |= U64W1(Qa0) | U64W1(Qa1) | U64W1(Qa2) | U64W1(Qa3) |
                      U64W1(Qa4) | U64W1(Qa5) | U64W1(Qa6) | U64W1(Qa7);
                s2 |= U64W0(Qb0) | U64W0(Qb1) | U64W0(Qb2) | U64W0(Qb3) |
                      U64W0(Qb4) | U64W0(Qb5) | U64W0(Qb6) | U64W0(Qb7);
                s3 |= U64W1(Qb0) | U64W1(Qb1) | U64W1(Qb2) | U64W1(Qb3) |
                      U64W1(Qb4) | U64W1(Qb5) | U64W1(Qb6) | U64W1(Qb7);
#undef U64W0
#undef U64W1
            }
        }
        tdA0 = nA0; tdA1 = nA1; tdA2 = nA2; tdA3 = nA3;
        tdB0 = nB0; tdB1 = nB1; tdB2 = nB2; tdB3 = nB3;
        tdC0 = nC0; tdC1 = nC1; tdC2 = nC2; tdC3 = nC3;
        tdD0 = nD0; tdD1 = nD1; tdD2 = nD2; tdD3 = nD3;
    }
#undef LOADTD

    __syncthreads();
    // scatter keep bits back to original index order
    for (int i = lane; i < N; i += 64) {
        unsigned char b = (unsigned char)((keepw_arr[i >> 6] >> (i & 63)) & 1ull);
        keepOrig[sidx[i]] = b;
    }
}

// Merged select (filter + first-K collection) + classify + epilogue.
__global__ void k_finish(const unsigned char* __restrict__ keepOrig,
                         const float* __restrict__ roi_boxes,
                         const float* __restrict__ roi_scores,
                         const float* __restrict__ det_boxes,
                         const float* __restrict__ info,
                         const float* __restrict__ vis,
                         const float* __restrict__ tf,
                         float* __restrict__ out) {
    __shared__ int wcnt[16];
    __shared__ int idxS[32];               // [31] = valid count
    __shared__ float feat[K * FEAT];       // 51200 B
    __shared__ float sc[K * NUM_CATS];     // 6500 B
    __shared__ float keyL[K];
    __shared__ int fgL[K];
    __shared__ int ordL[K];
    int tid = threadIdx.x;                 // 1024 threads
    if (tid < K) idxS[tid] = 0;
    __syncthreads();
    float sy = info[4], sx = info[5];

    // ---- select: first K valid in original-index order ----
    int base = 0;
    for (int ch = 0; ch < 16; ++ch) {
        int i = ch * 1024 + tid;
        bool keep = keepOrig[i] != 0;
        float4 rb = ((const float4*)roi_boxes)[i];
        bool nz = !((rb.x == 0.0f) && (rb.y == 0.0f) && (rb.z == 0.0f) && (rb.w == 0.0f));
        bool scr = roi_scores[i] >= 0.9f;
        float4 db = ((const float4*)det_boxes)[i];
        float r0 = db.x / sy, r1 = db.y / sx, r2 = db.z / sy, r3 = db.w / sx;
        bool big = ((r2 - r0) * (r3 - r1)) > 220.0f;
        bool valid = keep && nz && scr && big;
        unsigned long long bal = __ballot(valid);
        int wv = tid >> 6, lane = tid & 63;
        if (lane == 0) wcnt[wv] = (int)__popcll(bal);
        __syncthreads();
        int pre = 0, tot = 0;
        for (int w = 0; w < 16; ++w) { int cc = wcnt[w]; tot += cc; if (w < wv) pre += cc; }
        int rk = base + pre + (int)__popcll(bal & ((1ull << lane) - 1ull));
        if (valid && rk < K) idxS[rk] = i;
        base += tot;
        __syncthreads();
    }
    if (tid == 0) idxS[31] = base;
    __syncthreads();

    // ---- classify ----
    int count = idxS[31];
    int mincount = count < K ? count : K;

    for (int p = tid; p < K * FEAT; p += 1024) {
        int r = p >> 9, e = p & 511;
        feat[p] = vis[(size_t)idxS[r] * FEAT + e];
    }
    __syncthreads();

    for (int p = tid; p < K * NUM_CATS; p += 1024) {
        int r = p / NUM_CATS, c = p % NUM_CATS;
        const float* fr = &feat[r * FEAT];
        const float* tr = &tf[(size_t)c * FEAT];
        float s = 0.0f;
#pragma unroll 8
        for (int e = 0; e < FEAT; ++e) s += fr[e] * tr[e];
        sc[p] = s;
    }
    __syncthreads();

    if (tid < K) {
        float mv = sc[tid * NUM_CATS];
        int ma = 0;
        for (int c = 1; c < NUM_CATS; ++c) {
            float v = sc[tid * NUM_CATS + c];
            if (v > mv) { mv = v; ma = c; }     // first-max (jnp.argmax)
        }
        int fg = (tid < mincount) && (ma != 0);
        fgL[tid] = fg;
        keyL[tid] = fg ? mv : -INFINITY;
    }
    __syncthreads();

    if (tid == 0) {                 // stable selection sort, descending
        unsigned used = 0;
        for (int p = 0; p < K; ++p) {
            int bk = -1; float bv = 0.0f;
            for (int k2 = 0; k2 < K; ++k2) {
                if (used & (1u << k2)) continue;
                if (bk < 0 || keyL[k2] > bv) { bk = k2; bv = keyL[k2]; }
            }
            ordL[p] = bk;
            used |= (1u << bk);
        }
    }
    __syncthreads();

    // scores: [0 .. 1599]
    for (int p = tid; p < K * (NUM_CATS - 1); p += 1024) {
        int q = p >> 6, cc = p & 63;
        int src = ordL[q];
        out[p] = fgL[src] ? sc[src * NUM_CATS + cc + 1] : 0.0f;
    }
    // bboxes: [1600 .. 1699]  processed = [xmin, ymin, xmax, ymax]
    for (int p = tid; p < K * 4; p += 1024) {
        int q = p >> 2, e = p & 3;
        int src = ordL[q];
        float v = 0.0f;
        if (fgL[src]) {
            int o = idxS[src];
            float b0 = det_boxes[o * 4 + 0] / sy;   // ymin
            float b1 = det_boxes[o * 4 + 1] / sx;   // xmin
            float b2 = det_boxes[o * 4 + 2] / sy;   // ymax
            float b3 = det_boxes[o * 4 + 3] / sx;   // xmax
            v = (e == 0) ? b1 : (e == 1) ? b0 : (e == 2) ? b3 : b2;
        }
        out[1600 + p] = v;
    }
    // mask: [1700 .. 1724]
    if (tid < K) out[1700 + tid] = fgL[ordL[tid]] ? 1.0f : 0.0f;
}

extern "C" void kernel_launch(void* const* d_in, const int* in_sizes, int n_in,
                              void* d_out, int out_size, void* d_ws, size_t ws_size,
                              hipStream_t stream) {
    const float* roi_boxes  = (const float*)d_in[0];
    const float* roi_scores = (const float*)d_in[1];
    const float* det_boxes  = (const float*)d_in[2];
    // d_in[3] detection_masks: unused by reference
    const float* vis        = (const float*)d_in[4];
    const float* info       = (const float*)d_in[5];
    const float* tf         = (const float*)d_in[6];

    char* ws = (char*)d_ws;
    u64* keys                = (u64*)(ws + 0);
    unsigned int* rank       = (unsigned int*)(ws + 131072);
    unsigned int* sidx       = (unsigned int*)(ws + 196608);
    float4* sbox             = (float4*)(ws + 262144);
    float* sarea             = (float*)(ws + 524288);
    u64* mask                = (u64*)(ws + 589824);
    unsigned char* keepOrig  = (unsigned char*)(ws + 34144384);
    u64* zeropad             = (u64*)(ws + 34160768);
    u64* tdT                 = (u64*)(ws + 34162816);

    k_build<<<64, 256, 0, stream>>>(roi_scores, keys, rank, zeropad);
    k_rank<<<dim3(64, 8), 256, 0, stream>>>(keys, rank);
    k_scatter<<<64, 256, 0, stream>>>(rank, det_boxes, sidx, sbox, sarea);
    k_mask<<<dim3(64, 64), 256, 0, stream>>>(sbox, sarea, mask);
    k_tdiag<<<64, 256, 0, stream>>>(sbox, sarea, tdT);
    k_scan<<<1, 64, 0, stream>>>(mask, tdT, sidx, zeropad, keepOrig);
    k_finish<<<1, 1024, 0, stream>>>(keepOrig, roi_boxes, roi_scores, det_boxes,
                                     info, vis, tf, (float*)d_out);
}

// Round 7
// 726.645 us; speedup vs baseline: 1.0788x; 1.0788x over previous
//
#include <hip/hip_runtime.h>
#include <math.h>

#define N 16384
#define NWORDS 256       // N/64
#define FEAT 512
#define NUM_CATS 65
#define K 25
#define MAX_DETS 1000

typedef unsigned long long u64;
typedef unsigned int u32x4 __attribute__((ext_vector_type(4)));

// ---------------- ws layout (bytes) ----------------
// keys     : u64[N]            @ 0         (131072)  dead after k_rank;
//            tdiag u64[N] reuses this region (written by k_diag)
// rank     : u32[N]            @ 131072    (65536)
// sidx     : u32[N]            @ 196608    (65536)
// sbox     : float4[N]         @ 262144    (262144)
// sarea    : f32[N]            @ 524288    (65536)
// mask     : u64[N*NWORDS]     @ 589824    (33554432)
// keepOrig : u8[N]             @ 34144384  (16384)
// zeropad  : u64[256]          @ 34160768  (2048)   zeroed each launch by k_build
// flag     : u32               @ 34162816  (4)      scan-done flag for fillers
// total ~34.2 MB

// Sort key: descending by score, ties -> ascending original index.
// Also zeroes zeropad and the filler flag (ws re-poisoned each launch).
__global__ void k_build(const float* __restrict__ scores,
                        u64* __restrict__ keys,
                        unsigned int* __restrict__ rank,
                        u64* __restrict__ zeropad,
                        unsigned int* __restrict__ flag) {
    int i = blockIdx.x * 256 + threadIdx.x;
    keys[i] = ((u64)__float_as_uint(scores[i]) << 32) |
              (u64)(0xFFFFFFFFu - (unsigned)i);
    rank[i] = 0u;
    if (blockIdx.x == 0) zeropad[threadIdx.x] = 0ull;
    if (blockIdx.x == 0 && threadIdx.x == 0) atomicExch(flag, 0u);
}

// rank[i] = #{ j : key[j] > key[i] }  (keys distinct -> permutation)
__global__ void k_rank(const u64* __restrict__ keys,
                       unsigned int* __restrict__ rank) {
    __shared__ u64 lk[2048];
    int i = blockIdx.x * 256 + threadIdx.x;
    u64 my = keys[i];
    int j0 = blockIdx.y * 2048;
    for (int t = threadIdx.x; t < 2048; t += 256) lk[t] = keys[j0 + t];
    __syncthreads();
    unsigned int cnt = 0;
#pragma unroll 8
    for (int t = 0; t < 2048; ++t) cnt += (lk[t] > my) ? 1u : 0u;
    atomicAdd(&rank[i], cnt);
}

// Scatter into sorted order directly (merged scatter+gather).
__global__ void k_scatter(const unsigned int* __restrict__ rank,
                          const float* __restrict__ det_boxes,
                          unsigned int* __restrict__ sidx,
                          float4* __restrict__ sbox,
                          float* __restrict__ sarea) {
    int i = blockIdx.x * 256 + threadIdx.x;
    unsigned p = rank[i];
    sidx[p] = (unsigned)i;
    float4 b = ((const float4*)det_boxes)[i];   // [y1,x1,y2,x2]
    sbox[p] = b;
    sarea[p] = (b.w - b.y) * (b.z - b.x);       // (x2-x1)*(y2-y1)
}

// IoU>0.6 bit matrix, 256x256-box tiles per block (4 words/thread).
// Word (row, wi) written iff col0+63 >= row; fully-lower words stay
// garbage and are only ever OR'd into already-consumed supp words.
__global__ void k_mask(const float4* __restrict__ sbox,
                       const float* __restrict__ sarea,
                       u64* __restrict__ mask) {
    int cg = blockIdx.x, rg = blockIdx.y;
    if (cg < rg) return;                    // strictly lower 256-tile
    __shared__ float4 cbox[256];
    __shared__ float carea[256];
    int tid = threadIdx.x;
    cbox[tid] = sbox[cg * 256 + tid];
    carea[tid] = sarea[cg * 256 + tid];
    __syncthreads();
    int row = rg * 256 + tid;
    float4 r = sbox[row];
    float ra = sarea[row];
    for (int cw = 0; cw < 4; ++cw) {
        int col0 = cg * 256 + cw * 64;
        if (col0 + 63 < row) continue;
        u64 bits = 0ull;
        if (col0 > row) {
            for (int j = 0; j < 64; ++j) {
                float4 cbx = cbox[cw * 64 + j];
                float iw = fminf(r.w, cbx.w) - fmaxf(r.y, cbx.y);
                iw = fmaxf(iw, 0.0f);
                float ih = fminf(r.z, cbx.z) - fmaxf(r.x, cbx.x);
                ih = fmaxf(ih, 0.0f);
                float inter = iw * ih;
                float iou = inter / (ra + carea[cw * 64 + j] - inter + 1e-12f);
                if (iou > 0.6f) bits |= (1ull << j);
            }
        } else {
            for (int j = 0; j < 64; ++j) {
                int col = col0 + j;
                if (col > row) {
                    float4 cbx = cbox[cw * 64 + j];
                    float iw = fminf(r.w, cbx.w) - fmaxf(r.y, cbx.y);
                    iw = fmaxf(iw, 0.0f);
                    float ih = fminf(r.z, cbx.z) - fmaxf(r.x, cbx.x);
                    ih = fmaxf(ih, 0.0f);
                    float inter = iw * ih;
                    float iou = inter / (ra + carea[cw * 64 + j] - inter + 1e-12f);
                    if (iou > 0.6f) bits |= (1ull << j);
                }
            }
        }
        mask[(size_t)row * NWORDS + cg * 4 + cw] = bits;
    }
}

// Transposed diagonal blocks: tdiag[c*64+t] bit r (r<t) set iff box c*64+r
// suppresses box c*64+t. Same expression DAG as k_mask -> bitwise-identical.
__global__ void k_diag(const float4* __restrict__ sbox,
                       const float* __restrict__ sarea,
                       u64* __restrict__ tdiag) {
    __shared__ float4 b[64];
    __shared__ float a[64];
    int c = blockIdx.x, t = threadIdx.x;
    b[t] = sbox[c * 64 + t];
    a[t] = sarea[c * 64 + t];
    __syncthreads();
    float4 mybox = b[t];
    float myarea = a[t];
    u64 bits = 0ull;
    for (int r = 0; r < 64; ++r) {
        if (r < t) {
            float4 rb = b[r];
            float iw = fminf(rb.w, mybox.w) - fmaxf(rb.y, mybox.y);
            iw = fmaxf(iw, 0.0f);
            float ih = fminf(rb.z, mybox.z) - fmaxf(rb.x, mybox.x);
            ih = fmaxf(ih, 0.0f);
            float inter = iw * ih;
            float iou = inter / (a[r] + myarea - inter + 1e-12f);
            if (iou > 0.6f) bits |= (1ull << r);
        }
    }
    tdiag[c * 64 + t] = bits;
}

// Block 0: round-5 single-wave greedy scan (ballot phase A + asm-batched
// phase B) — bitwise-verified structure. Blocks 1..255: clock-boost
// fillers — dense FMA spin until block 0 raises the device-scope flag.
// Tests the hypothesis that the scan's 240-340us invariance across
// structures is DPM downclocking on a near-idle chip.
__global__ void __launch_bounds__(64, 1)
k_scan(const u64* __restrict__ mask,
       const u64* __restrict__ tdiag,
       const unsigned int* __restrict__ sidx,
       const u64* __restrict__ zeropad,
       unsigned char* __restrict__ keepOrig,
       unsigned int* __restrict__ flag) {
    int lane = threadIdx.x;                       // 64 threads = 1 wave

    if (blockIdx.x != 0) {
        // ---- filler: burn VALU to hold clocks up, poll flag ----
        float acc = (float)lane + (float)blockIdx.x * 0.001f;
        for (;;) {
            if (atomicOr(flag, 0u) != 0u) break;  // device-scope read
#pragma unroll 16
            for (int it = 0; it < 4096; ++it)
                acc = fmaf(acc, 1.0000001f, 0.25f);
        }
        asm volatile("" :: "v"(acc));             // keep the burn alive
        return;
    }

    __shared__ u64 keepw_arr[NWORDS];
    u64 s0 = 0, s1 = 0, s2 = 0, s3 = 0;           // supp words lane*4+0..3
    int cnt = 0;                                  // uniform across lanes
    const char* zp = (const char*)zeropad + lane * 32;

    u64 colnext = tdiag[lane];                    // chunk 0 column prefetch

    for (int c = 0; c < NWORDS; ++c) {
        if (cnt >= MAX_DETS) {                    // nothing further kept/suppressed
            for (int cc = c + lane; cc < NWORDS; cc += 64) keepw_arr[cc] = 0ull;
            break;
        }
        u64 mycol = colnext;
        if (c + 1 < NWORDS)                       // prefetch next chunk's column
            colnext = tdiag[(c + 1) * 64 + lane];

        // broadcast supp word c from its owner lane/reg (one shfl per chunk)
        u64 sw;
        switch (c & 3) {
            case 0: sw = s0; break;
            case 1: sw = s1; break;
            case 2: sw = s2; break;
            default: sw = s3; break;
        }
        sw = __shfl(sw, c >> 2, 64);

        // ---- phase A: ballot greedy, no cross-lane data movement ----
        bool alive = !((sw >> lane) & 1ull);
        u64 keepw = 0ull;                         // uniform on all lanes
        while (cnt < MAX_DETS) {
            u64 bal = __ballot(alive);
            if (!bal) break;
            int k = __ffsll((long long)bal) - 1;  // lowest alive -> kept
            keepw |= 1ull << k;
            ++cnt;
            alive = alive && !((mycol >> k) & 1ull) && (lane != k);
        }
        if (lane == 0) keepw_arr[c] = keepw;

        // ---- phase B: batched suppression OR, 8 rows per asm batch ----
        if (cnt < MAX_DETS && keepw) {
            u64 kw = keepw;
            size_t rbase = (size_t)(c * 64);
            while (kw) {
                const char *P0, *P1, *P2, *P3, *P4, *P5, *P6, *P7;
#define FILL(Pi)                                                              \
                {                                                             \
                    if (kw) {                                                 \
                        int t = __ffsll((long long)kw) - 1; kw &= kw - 1;     \
                        Pi = (const char*)mask +                              \
                             (((rbase + (size_t)t) << 8) + ((size_t)lane << 2)) * 8; \
                    } else Pi = zp;                                           \
                }
                FILL(P0) FILL(P1) FILL(P2) FILL(P3)
                FILL(P4) FILL(P5) FILL(P6) FILL(P7)
#undef FILL
                u32x4 Qa0, Qb0, Qa1, Qb1, Qa2, Qb2, Qa3, Qb3;
                u32x4 Qa4, Qb4, Qa5, Qb5, Qa6, Qb6, Qa7, Qb7;
                asm volatile(
                    "global_load_dwordx4 %0, %16, off\n\t"
                    "global_load_dwordx4 %1, %16, off offset:16\n\t"
                    "global_load_dwordx4 %2, %17, off\n\t"
                    "global_load_dwordx4 %3, %17, off offset:16\n\t"
                    "global_load_dwordx4 %4, %18, off\n\t"
                    "global_load_dwordx4 %5, %18, off offset:16\n\t"
                    "global_load_dwordx4 %6, %19, off\n\t"
                    "global_load_dwordx4 %7, %19, off offset:16\n\t"
                    "global_load_dwordx4 %8, %20, off\n\t"
                    "global_load_dwordx4 %9, %20, off offset:16\n\t"
                    "global_load_dwordx4 %10, %21, off\n\t"
                    "global_load_dwordx4 %11, %21, off offset:16\n\t"
                    "global_load_dwordx4 %12, %22, off\n\t"
                    "global_load_dwordx4 %13, %22, off offset:16\n\t"
                    "global_load_dwordx4 %14, %23, off\n\t"
                    "global_load_dwordx4 %15, %23, off offset:16\n\t"
                    "s_waitcnt vmcnt(0)"
                    : "=&v"(Qa0), "=&v"(Qb0), "=&v"(Qa1), "=&v"(Qb1),
                      "=&v"(Qa2), "=&v"(Qb2), "=&v"(Qa3), "=&v"(Qb3),
                      "=&v"(Qa4), "=&v"(Qb4), "=&v"(Qa5), "=&v"(Qb5),
                      "=&v"(Qa6), "=&v"(Qb6), "=&v"(Qa7), "=&v"(Qb7)
                    : "v"(P0), "v"(P1), "v"(P2), "v"(P3),
                      "v"(P4), "v"(P5), "v"(P6), "v"(P7)
                    : "memory");
#define U64W0(q) (((u64)(q).y << 32) | (u64)(q).x)
#define U64W1(q) (((u64)(q).w << 32) | (u64)(q).z)
                s0 |= U64W0(Qa0) | U64W0(Qa1) | U64W0(Qa2) | U64W0(Qa3) |
                      U64W0(Qa4) | U64W0(Qa5) | U64W0(Qa6) | U64W0(Qa7);
                s1 |= U64W1(Qa0) | U64W1(Qa1) | U64W1(Qa2) | U64W1(Qa3) |
                      U64W1(Qa4) | U64W1(Qa5) | U64W1(Qa6) | U64W1(Qa7);
                s2 |= U64W0(Qb0) | U64W0(Qb1) | U64W0(Qb2) | U64W0(Qb3) |
                      U64W0(Qb4) | U64W0(Qb5) | U64W0(Qb6) | U64W0(Qb7);
                s3 |= U64W1(Qb0) | U64W1(Qb1) | U64W1(Qb2) | U64W1(Qb3) |
                      U64W1(Qb4) | U64W1(Qb5) | U64W1(Qb6) | U64W1(Qb7);
#undef U64W0
#undef U64W1
            }
        }
    }

    __syncthreads();
    // scatter keep bits back to original index order
    for (int i = lane; i < N; i += 64) {
        unsigned char b = (unsigned char)((keepw_arr[i >> 6] >> (i & 63)) & 1ull);
        keepOrig[sidx[i]] = b;
    }
    __threadfence();                               // keepOrig visible first
    if (lane == 0) atomicExch(flag, 1u);           // release fillers
}

// Merged select (filter + first-K collection) + classify + epilogue.
__global__ void k_finish(const unsigned char* __restrict__ keepOrig,
                         const float* __restrict__ roi_boxes,
                         const float* __restrict__ roi_scores,
                         const float* __restrict__ det_boxes,
                         const float* __restrict__ info,
                         const float* __restrict__ vis,
                         const float* __restrict__ tf,
                         float* __restrict__ out) {
    __shared__ int wcnt[16];
    __shared__ int idxS[32];               // [31] = valid count
    __shared__ float feat[K * FEAT];       // 51200 B
    __shared__ float sc[K * NUM_CATS];     // 6500 B
    __shared__ float keyL[K];
    __shared__ int fgL[K];
    __shared__ int ordL[K];
    int tid = threadIdx.x;                 // 1024 threads
    if (tid < K) idxS[tid] = 0;
    __syncthreads();
    float sy = info[4], sx = info[5];

    // ---- select: first K valid in original-index order ----
    int base = 0;
    for (int ch = 0; ch < 16; ++ch) {
        int i = ch * 1024 + tid;
        bool keep = keepOrig[i] != 0;
        float4 rb = ((const float4*)roi_boxes)[i];
        bool nz = !((rb.x == 0.0f) && (rb.y == 0.0f) && (rb.z == 0.0f) && (rb.w == 0.0f));
        bool scr = roi_scores[i] >= 0.9f;
        float4 db = ((const float4*)det_boxes)[i];
        float r0 = db.x / sy, r1 = db.y / sx, r2 = db.z / sy, r3 = db.w / sx;
        bool big = ((r2 - r0) * (r3 - r1)) > 220.0f;
        bool valid = keep && nz && scr && big;
        unsigned long long bal = __ballot(valid);
        int wv = tid >> 6, lane = tid & 63;
        if (lane == 0) wcnt[wv] = (int)__popcll(bal);
        __syncthreads();
        int pre = 0, tot = 0;
        for (int w = 0; w < 16; ++w) { int cc = wcnt[w]; tot += cc; if (w < wv) pre += cc; }
        int rk = base + pre + (int)__popcll(bal & ((1ull << lane) - 1ull));
        if (valid && rk < K) idxS[rk] = i;
        base += tot;
        __syncthreads();
    }
    if (tid == 0) idxS[31] = base;
    __syncthreads();

    // ---- classify ----
    int count = idxS[31];
    int mincount = count < K ? count : K;

    for (int p = tid; p < K * FEAT; p += 1024) {
        int r = p >> 9, e = p & 511;
        feat[p] = vis[(size_t)idxS[r] * FEAT + e];
    }
    __syncthreads();

    for (int p = tid; p < K * NUM_CATS; p += 1024) {
        int r = p / NUM_CATS, c = p % NUM_CATS;
        const float* fr = &feat[r * FEAT];
        const float* tr = &tf[(size_t)c * FEAT];
        float s = 0.0f;
#pragma unroll 8
        for (int e = 0; e < FEAT; ++e) s += fr[e] * tr[e];
        sc[p] = s;
    }
    __syncthreads();

    if (tid < K) {
        float mv = sc[tid * NUM_CATS];
        int ma = 0;
        for (int c = 1; c < NUM_CATS; ++c) {
            float v = sc[tid * NUM_CATS + c];
            if (v > mv) { mv = v; ma = c; }     // first-max (jnp.argmax)
        }
        int fg = (tid < mincount) && (ma != 0);
        fgL[tid] = fg;
        keyL[tid] = fg ? mv : -INFINITY;
    }
    __syncthreads();

    if (tid == 0) {                 // stable selection sort, descending
        unsigned used = 0;
        for (int p = 0; p < K; ++p) {
            int bk = -1; float bv = 0.0f;
            for (int k2 = 0; k2 < K; ++k2) {
                if (used & (1u << k2)) continue;
                if (bk < 0 || keyL[k2] > bv) { bk = k2; bv = keyL[k2]; }
            }
            ordL[p] = bk;
            used |= (1u << bk);
        }
    }
    __syncthreads();

    // scores: [0 .. 1599]
    for (int p = tid; p < K * (NUM_CATS - 1); p += 1024) {
        int q = p >> 6, cc = p & 63;
        int src = ordL[q];
        out[p] = fgL[src] ? sc[src * NUM_CATS + cc + 1] : 0.0f;
    }
    // bboxes: [1600 .. 1699]  processed = [xmin, ymin, xmax, ymax]
    for (int p = tid; p < K * 4; p += 1024) {
        int q = p >> 2, e = p & 3;
        int src = ordL[q];
        float v = 0.0f;
        if (fgL[src]) {
            int o = idxS[src];
            float b0 = det_boxes[o * 4 + 0] / sy;   // ymin
            float b1 = det_boxes[o * 4 + 1] / sx;   // xmin
            float b2 = det_boxes[o * 4 + 2] / sy;   // ymax
            float b3 = det_boxes[o * 4 + 3] / sx;   // xmax
            v = (e == 0) ? b1 : (e == 1) ? b0 : (e == 2) ? b3 : b2;
        }
        out[1600 + p] = v;
    }
    // mask: [1700 .. 1724]
    if (tid < K) out[1700 + tid] = fgL[ordL[tid]] ? 1.0f : 0.0f;
}

extern "C" void kernel_launch(void* const* d_in, const int* in_sizes, int n_in,
                              void* d_out, int out_size, void* d_ws, size_t ws_size,
                              hipStream_t stream) {
    const float* roi_boxes  = (const float*)d_in[0];
    const float* roi_scores = (const float*)d_in[1];
    const float* det_boxes  = (const float*)d_in[2];
    // d_in[3] detection_masks: unused by reference
    const float* vis        = (const float*)d_in[4];
    const float* info       = (const float*)d_in[5];
    const float* tf         = (const float*)d_in[6];

    char* ws = (char*)d_ws;
    u64* keys                = (u64*)(ws + 0);        // dead after k_rank
    u64* tdiag               = (u64*)(ws + 0);        // reuses keys' region
    unsigned int* rank       = (unsigned int*)(ws + 131072);
    unsigned int* sidx       = (unsigned int*)(ws + 196608);
    float4* sbox             = (float4*)(ws + 262144);
    float* sarea             = (float*)(ws + 524288);
    u64* mask                = (u64*)(ws + 589824);
    unsigned char* keepOrig  = (unsigned char*)(ws + 34144384);
    u64* zeropad             = (u64*)(ws + 34160768);
    unsigned int* flag       = (unsigned int*)(ws + 34162816);

    k_build<<<64, 256, 0, stream>>>(roi_scores, keys, rank, zeropad, flag);
    k_rank<<<dim3(64, 8), 256, 0, stream>>>(keys, rank);
    k_scatter<<<64, 256, 0, stream>>>(rank, det_boxes, sidx, sbox, sarea);
    k_mask<<<dim3(64, 64), 256, 0, stream>>>(sbox, sarea, mask);
    k_diag<<<256, 64, 0, stream>>>(sbox, sarea, tdiag);
    k_scan<<<256, 64, 0, stream>>>(mask, tdiag, sidx, zeropad, keepOrig, flag);
    k_finish<<<1, 1024, 0, stream>>>(keepOrig, roi_boxes, roi_scores, det_boxes,
                                     info, vis, tf, (float*)d_out);
}

// Round 8
// 685.120 us; speedup vs baseline: 1.1442x; 1.0606x over previous
//
#include <hip/hip_runtime.h>
#include <math.h>

#define N 16384
#define NWORDS 256       // N/64
#define FEAT 512
#define NUM_CATS 65
#define K 25
#define MAX_DETS 1000
#define NSUP 3           // register-corrected lookback chunks (c-1..c-3)
#define NWK 7            // worker waves

typedef unsigned long long u64;

// ---------------- ws layout (bytes) ----------------
// keys     : u64[N]            @ 0         (131072)
// rank     : u32[N]            @ 131072    (65536)
// sidx     : u32[N]            @ 196608    (65536)
// sbox     : float4[N]         @ 262144    (262144)
// sarea    : f32[N]            @ 524288    (65536)
// mask     : u64[N*NWORDS]     @ 589824    (33554432) -> ends 34144256
// keepOrig : u8[N]             @ 34144256  (16384)    -> ends 34160640
// tsup     : u64[256*64*4]     @ 34160640  (524288)   -> ends 34684928
//            record (c*64+lane): [d0=tdiag, d1, d2, d3]

// Sort key: descending by score, ties -> ascending original index.
__global__ void k_build(const float* __restrict__ scores,
                        u64* __restrict__ keys,
                        unsigned int* __restrict__ rank) {
    int i = blockIdx.x * 256 + threadIdx.x;
    keys[i] = ((u64)__float_as_uint(scores[i]) << 32) |
              (u64)(0xFFFFFFFFu - (unsigned)i);
    rank[i] = 0u;
}

// rank[i] = #{ j : key[j] > key[i] }  (keys distinct -> permutation)
__global__ void k_rank(const u64* __restrict__ keys,
                       unsigned int* __restrict__ rank) {
    __shared__ u64 lk[2048];
    int i = blockIdx.x * 256 + threadIdx.x;
    u64 my = keys[i];
    int j0 = blockIdx.y * 2048;
    for (int t = threadIdx.x; t < 2048; t += 256) lk[t] = keys[j0 + t];
    __syncthreads();
    unsigned int cnt = 0;
#pragma unroll 8
    for (int t = 0; t < 2048; ++t) cnt += (lk[t] > my) ? 1u : 0u;
    atomicAdd(&rank[i], cnt);
}

// Scatter into sorted order directly (merged scatter+gather).
__global__ void k_scatter(const unsigned int* __restrict__ rank,
                          const float* __restrict__ det_boxes,
                          unsigned int* __restrict__ sidx,
                          float4* __restrict__ sbox,
                          float* __restrict__ sarea) {
    int i = blockIdx.x * 256 + threadIdx.x;
    unsigned p = rank[i];
    sidx[p] = (unsigned)i;
    float4 b = ((const float4*)det_boxes)[i];   // [y1,x1,y2,x2]
    sbox[p] = b;
    sarea[p] = (b.w - b.y) * (b.z - b.x);       // (x2-x1)*(y2-y1)
}

// IoU>0.6 bit matrix, 256x256-box tiles per block (4 words/thread).
// Word (row, wi) written iff col0+63 >= row; fully-lower words stay
// garbage and are only ever OR'd into already-consumed supp words.
__global__ void k_mask(const float4* __restrict__ sbox,
                       const float* __restrict__ sarea,
                       u64* __restrict__ mask) {
    int cg = blockIdx.x, rg = blockIdx.y;
    if (cg < rg) return;                    // strictly lower 256-tile
    __shared__ float4 cbox[256];
    __shared__ float carea[256];
    int tid = threadIdx.x;
    cbox[tid] = sbox[cg * 256 + tid];
    carea[tid] = sarea[cg * 256 + tid];
    __syncthreads();
    int row = rg * 256 + tid;
    float4 r = sbox[row];
    float ra = sarea[row];
    for (int cw = 0; cw < 4; ++cw) {
        int col0 = cg * 256 + cw * 64;
        if (col0 + 63 < row) continue;
        u64 bits = 0ull;
        if (col0 > row) {
            for (int j = 0; j < 64; ++j) {
                float4 cbx = cbox[cw * 64 + j];
                float iw = fminf(r.w, cbx.w) - fmaxf(r.y, cbx.y);
                iw = fmaxf(iw, 0.0f);
                float ih = fminf(r.z, cbx.z) - fmaxf(r.x, cbx.x);
                ih = fmaxf(ih, 0.0f);
                float inter = iw * ih;
                float iou = inter / (ra + carea[cw * 64 + j] - inter + 1e-12f);
                if (iou > 0.6f) bits |= (1ull << j);
            }
        } else {
            for (int j = 0; j < 64; ++j) {
                int col = col0 + j;
                if (col > row) {
                    float4 cbx = cbox[cw * 64 + j];
                    float iw = fminf(r.w, cbx.w) - fmaxf(r.y, cbx.y);
                    iw = fmaxf(iw, 0.0f);
                    float ih = fminf(r.z, cbx.z) - fmaxf(r.x, cbx.x);
                    ih = fmaxf(ih, 0.0f);
                    float inter = iw * ih;
                    float iou = inter / (ra + carea[cw * 64 + j] - inter + 1e-12f);
                    if (iou > 0.6f) bits |= (1ull << j);
                }
            }
        }
        mask[(size_t)row * NWORDS + cg * 4 + cw] = bits;
    }
}

// Transposed (column-major) suppression records for the scan's register
// lookback. For chunk c, column l, offset d (0..3):
//   bit r set iff box (c-d)*64+r suppresses box c*64+l
//   (d==0 additionally requires r < l; c<d records are written as 0).
// Same IoU expression DAG as k_mask (row box = suppressor, row area first)
// -> bitwise-identical decisions (invariant held since round 1).
__global__ void k_tsup(const float4* __restrict__ sbox,
                       const float* __restrict__ sarea,
                       u64* __restrict__ tsup) {
    int c = blockIdx.x, l = threadIdx.x;
    float4 my = sbox[c * 64 + l];
    float myarea = sarea[c * 64 + l];
#pragma unroll
    for (int d = 0; d <= NSUP; ++d) {
        u64 bits = 0ull;
        if (c >= d) {
            int rb0 = (c - d) * 64;
            for (int r = 0; r < 64; ++r) {
                if (d == 0 && r >= l) break;
                float4 rb = sbox[rb0 + r];
                float ra = sarea[rb0 + r];
                float iw = fminf(rb.w, my.w) - fmaxf(rb.y, my.y);
                iw = fmaxf(iw, 0.0f);
                float ih = fminf(rb.z, my.z) - fmaxf(rb.x, my.x);
                ih = fmaxf(ih, 0.0f);
                float inter = iw * ih;
                float iou = inter / (ra + myarea - inter + 1e-12f);
                if (iou > 0.6f) bits |= (1ull << r);
            }
        }
        tsup[((size_t)c * 64 + l) * 4 + d] = bits;
    }
}

// Pipelined greedy scan, one block of 8 waves.
// Wave 0 (decision): per chunk c, alive = LDS supp word c (complete through
// chunk c-4 keeps, guaranteed by bcount handshake) corrected with
// register ANDs against tsup d=1..3 and the last 3 keep-masks; then the
// proven R5 ballot-greedy with tsup d=0 (tdiag). NO global-memory wait on
// the critical path: tsup records are prefetched 3 chunks ahead (3
// outstanding loads cover latency at ~450cyc/chunk).
// Waves 1..7 (workers): after wave 0 publishes chunk j, OR the kept rows'
// full mask rows into LDS supp (rows rotated (j+rank)%7 across workers so
// no worker serializes back-to-back HBM loads); deadline = 4 chunk
// periods. 32-bit LDS atomics; duplicate ORs for chunks c-3..c-1 are
// idempotent with the register corrections.
__global__ void __launch_bounds__(512, 1)
k_scan(const u64* __restrict__ mask,
       const u64* __restrict__ tsup,
       const unsigned int* __restrict__ sidx,
       unsigned char* __restrict__ keepOrig) {
    __shared__ u64 supp[NWORDS];
    __shared__ u64 keepw_arr[NWORDS];
    __shared__ int bcount[NWORDS];
    __shared__ int progress_s;
    int tid = threadIdx.x;
    int wave = tid >> 6, lane = tid & 63;
    for (int i = tid; i < NWORDS; i += 512) {
        supp[i] = 0ull; keepw_arr[i] = 0ull; bcount[i] = 0;
    }
    if (tid == 0) progress_s = -1;
    __syncthreads();

    volatile int* vprog = &progress_s;
    volatile int* vb = bcount;

    if (wave == 0) {
        // ---------------- decision wave ----------------
        u64 kw1 = 0, kw2 = 0, kw3 = 0;
        int cnt = 0, bptr = 0;
        const ulonglong4* tp = (const ulonglong4*)tsup;
        ulonglong4 t0 = tp[0 * 64 + lane];
        ulonglong4 t1 = tp[1 * 64 + lane];
        ulonglong4 t2 = tp[2 * 64 + lane];
        for (int c = 0; c < NWORDS; ++c) {
            if (cnt >= MAX_DETS) break;       // keepw_arr already 0 for rest
            ulonglong4 cur = t0; t0 = t1; t1 = t2;
            if (c + 3 < NWORDS) t2 = tp[(size_t)(c + 3) * 64 + lane];

            // ensure supp[c] complete through chunk c-1-NSUP
            while (bptr <= c - 1 - NSUP) {
                while (vb[bptr] < NWK) {}
                ++bptr;
            }
            u64 sw = *((volatile u64*)&supp[c]);
            bool alive = !((sw >> lane) & 1ull) &&
                         ((cur.y & kw1) == 0ull) &&
                         ((cur.z & kw2) == 0ull) &&
                         ((cur.w & kw3) == 0ull);
            u64 mycol = cur.x;

            u64 keepw = 0ull;                 // uniform on all lanes
            while (cnt < MAX_DETS) {
                u64 bal = __ballot(alive);
                if (!bal) break;
                int k = __ffsll((long long)bal) - 1;
                keepw |= 1ull << k;
                ++cnt;
                alive = alive && !((mycol >> k) & 1ull) && (lane != k);
            }
            if (lane == 0) keepw_arr[c] = keepw;
            __threadfence_block();            // keepw visible before progress
            if (lane == 0) *vprog = c;
            kw3 = kw2; kw2 = kw1; kw1 = keepw;
        }
        __threadfence_block();
        if (lane == 0) *vprog = NWORDS - 1;   // release workers past any cap-break
    } else {
        // ---------------- worker waves ----------------
        int w = wave - 1;                     // 0..6
        for (int j = 0; j < NWORDS; ++j) {
            while (*vprog < j) __builtin_amdgcn_s_sleep(1);
            u64 kw = *((volatile u64*)&keepw_arr[j]);
            u64 L0 = 0, L1 = 0, L2 = 0, L3 = 0;
            int r = 0; bool got = false;
            while (kw) {
                int t = __ffsll((long long)kw) - 1; kw &= kw - 1ull;
                if ((j + r) % NWK == w) {
                    const ulonglong2* p =
                        (const ulonglong2*)(mask + (((size_t)j * 64 + t) << 8)
                                            + (size_t)lane * 4);
                    ulonglong2 a = p[0], b = p[1];
                    L0 |= a.x; L1 |= a.y; L2 |= b.x; L3 |= b.y;
                    got = true;
                }
                ++r;
            }
            if (got) {
                unsigned* s32 = (unsigned*)&supp[(size_t)lane * 4];
                if (L0) { atomicOr(s32 + 0, (unsigned)L0); atomicOr(s32 + 1, (unsigned)(L0 >> 32)); }
                if (L1) { atomicOr(s32 + 2, (unsigned)L1); atomicOr(s32 + 3, (unsigned)(L1 >> 32)); }
                if (L2) { atomicOr(s32 + 4, (unsigned)L2); atomicOr(s32 + 5, (unsigned)(L2 >> 32)); }
                if (L3) { atomicOr(s32 + 6, (unsigned)L3); atomicOr(s32 + 7, (unsigned)(L3 >> 32)); }
            }
            __threadfence_block();
            if (lane == 0) atomicAdd(&bcount[j], 1);
        }
    }

    __syncthreads();
    // scatter keep bits back to original index order
    for (int i = tid; i < N; i += 512) {
        keepOrig[sidx[i]] =
            (unsigned char)((keepw_arr[i >> 6] >> (i & 63)) & 1ull);
    }
}

// Merged select (filter + first-K collection) + classify + epilogue.
__global__ void k_finish(const unsigned char* __restrict__ keepOrig,
                         const float* __restrict__ roi_boxes,
                         const float* __restrict__ roi_scores,
                         const float* __restrict__ det_boxes,
                         const float* __restrict__ info,
                         const float* __restrict__ vis,
                         const float* __restrict__ tf,
                         float* __restrict__ out) {
    __shared__ int wcnt[16];
    __shared__ int idxS[32];               // [31] = valid count
    __shared__ float feat[K * FEAT];       // 51200 B
    __shared__ float sc[K * NUM_CATS];     // 6500 B
    __shared__ float keyL[K];
    __shared__ int fgL[K];
    __shared__ int ordL[K];
    int tid = threadIdx.x;                 // 1024 threads
    if (tid < K) idxS[tid] = 0;
    __syncthreads();
    float sy = info[4], sx = info[5];

    // ---- select: first K valid in original-index order ----
    int base = 0;
    for (int ch = 0; ch < 16; ++ch) {
        int i = ch * 1024 + tid;
        bool keep = keepOrig[i] != 0;
        float4 rb = ((const float4*)roi_boxes)[i];
        bool nz = !((rb.x == 0.0f) && (rb.y == 0.0f) && (rb.z == 0.0f) && (rb.w == 0.0f));
        bool scr = roi_scores[i] >= 0.9f;
        float4 db = ((const float4*)det_boxes)[i];
        float r0 = db.x / sy, r1 = db.y / sx, r2 = db.z / sy, r3 = db.w / sx;
        bool big = ((r2 - r0) * (r3 - r1)) > 220.0f;
        bool valid = keep && nz && scr && big;
        unsigned long long bal = __ballot(valid);
        int wv = tid >> 6, lane = tid & 63;
        if (lane == 0) wcnt[wv] = (int)__popcll(bal);
        __syncthreads();
        int pre = 0, tot = 0;
        for (int w = 0; w < 16; ++w) { int cc = wcnt[w]; tot += cc; if (w < wv) pre += cc; }
        int rk = base + pre + (int)__popcll(bal & ((1ull << lane) - 1ull));
        if (valid && rk < K) idxS[rk] = i;
        base += tot;
        __syncthreads();
    }
    if (tid == 0) idxS[31] = base;
    __syncthreads();

    // ---- classify ----
    int count = idxS[31];
    int mincount = count < K ? count : K;

    for (int p = tid; p < K * FEAT; p += 1024) {
        int r = p >> 9, e = p & 511;
        feat[p] = vis[(size_t)idxS[r] * FEAT + e];
    }
    __syncthreads();

    for (int p = tid; p < K * NUM_CATS; p += 1024) {
        int r = p / NUM_CATS, c = p % NUM_CATS;
        const float* fr = &feat[r * FEAT];
        const float* tr = &tf[(size_t)c * FEAT];
        float s = 0.0f;
#pragma unroll 8
        for (int e = 0; e < FEAT; ++e) s += fr[e] * tr[e];
        sc[p] = s;
    }
    __syncthreads();

    if (tid < K) {
        float mv = sc[tid * NUM_CATS];
        int ma = 0;
        for (int c = 1; c < NUM_CATS; ++c) {
            float v = sc[tid * NUM_CATS + c];
            if (v > mv) { mv = v; ma = c; }     // first-max (jnp.argmax)
        }
        int fg = (tid < mincount) && (ma != 0);
        fgL[tid] = fg;
        keyL[tid] = fg ? mv : -INFINITY;
    }
    __syncthreads();

    if (tid == 0) {                 // stable selection sort, descending
        unsigned used = 0;
        for (int p = 0; p < K; ++p) {
            int bk = -1; float bv = 0.0f;
            for (int k2 = 0; k2 < K; ++k2) {
                if (used & (1u << k2)) continue;
                if (bk < 0 || keyL[k2] > bv) { bk = k2; bv = keyL[k2]; }
            }
            ordL[p] = bk;
            used |= (1u << bk);
        }
    }
    __syncthreads();

    // scores: [0 .. 1599]
    for (int p = tid; p < K * (NUM_CATS - 1); p += 1024) {
        int q = p >> 6, cc = p & 63;
        int src = ordL[q];
        out[p] = fgL[src] ? sc[src * NUM_CATS + cc + 1] : 0.0f;
    }
    // bboxes: [1600 .. 1699]  processed = [xmin, ymin, xmax, ymax]
    for (int p = tid; p < K * 4; p += 1024) {
        int q = p >> 2, e = p & 3;
        int src = ordL[q];
        float v = 0.0f;
        if (fgL[src]) {
            int o = idxS[src];
            float b0 = det_boxes[o * 4 + 0] / sy;   // ymin
            float b1 = det_boxes[o * 4 + 1] / sx;   // xmin
            float b2 = det_boxes[o * 4 + 2] / sy;   // ymax
            float b3 = det_boxes[o * 4 + 3] / sx;   // xmax
            v = (e == 0) ? b1 : (e == 1) ? b0 : (e == 2) ? b3 : b2;
        }
        out[1600 + p] = v;
    }
    // mask: [1700 .. 1724]
    if (tid < K) out[1700 + tid] = fgL[ordL[tid]] ? 1.0f : 0.0f;
}

extern "C" void kernel_launch(void* const* d_in, const int* in_sizes, int n_in,
                              void* d_out, int out_size, void* d_ws, size_t ws_size,
                              hipStream_t stream) {
    const float* roi_boxes  = (const float*)d_in[0];
    const float* roi_scores = (const float*)d_in[1];
    const float* det_boxes  = (const float*)d_in[2];
    // d_in[3] detection_masks: unused by reference
    const float* vis        = (const float*)d_in[4];
    const float* info       = (const float*)d_in[5];
    const float* tf         = (const float*)d_in[6];

    char* ws = (char*)d_ws;
    u64* keys                = (u64*)(ws + 0);
    unsigned int* rank       = (unsigned int*)(ws + 131072);
    unsigned int* sidx       = (unsigned int*)(ws + 196608);
    float4* sbox             = (float4*)(ws + 262144);
    float* sarea             = (float*)(ws + 524288);
    u64* mask                = (u64*)(ws + 589824);
    unsigned char* keepOrig  = (unsigned char*)(ws + 34144256);
    u64* tsup                = (u64*)(ws + 34160640);

    k_build<<<64, 256, 0, stream>>>(roi_scores, keys, rank);
    k_rank<<<dim3(64, 8), 256, 0, stream>>>(keys, rank);
    k_scatter<<<64, 256, 0, stream>>>(rank, det_boxes, sidx, sbox, sarea);
    k_mask<<<dim3(64, 64), 256, 0, stream>>>(sbox, sarea, mask);
    k_tsup<<<256, 64, 0, stream>>>(sbox, sarea, tsup);
    k_scan<<<1, 512, 0, stream>>>(mask, tsup, sidx, keepOrig);
    k_finish<<<1, 1024, 0, stream>>>(keepOrig, roi_boxes, roi_scores, det_boxes,
                                     info, vis, tf, (float*)d_out);
}